// Round 7
// baseline (328.015 us; speedup 1.0000x reference)
//
#include <hip/hip_runtime.h>

// ---------------------------------------------------------------------------
// CausalSelfAttention fused block, MI355X (gfx950)
// Round 6: round-5 occupancy levers (bf16-packed LSE combine -> 18 KB LDS,
// launch_bounds(256,5), setprio) with the permlane32_swap experiment REVERTED
// to the round-4-verified __shfl_xor exchanges (round 5 failed correctness on
// the permlane lane-convention). GEMMs (m97 LDS), rope, cvt unchanged.
// ---------------------------------------------------------------------------

typedef __attribute__((ext_vector_type(8)))  short  short8;
typedef __attribute__((ext_vector_type(4)))  float  f32x4;
typedef __attribute__((ext_vector_type(16))) float  f32x16;
typedef __attribute__((ext_vector_type(4)))  float  float4v;
typedef __attribute__((ext_vector_type(4)))  unsigned short ushort4v;
typedef __attribute__((ext_vector_type(4)))  unsigned int   uint4v;

#define S_LEN 4096
#define DMODEL 1024
#define NHEADS 16
#define DKH 64

// 0.125 * log2(e): folds 1/sqrt(64) and the exp->exp2 conversion into Q.
#define QSCALE 0.18033688011112042f

__device__ __forceinline__ unsigned short f2bf(float f) {
  unsigned u = __builtin_bit_cast(unsigned, f);
  u += 0x7FFFu + ((u >> 16) & 1u);   // round-to-nearest-even
  return (unsigned short)(u >> 16);
}
__device__ __forceinline__ float bf2f(unsigned short h) {
  return __builtin_bit_cast(float, ((unsigned)h) << 16);
}

// async global->LDS, 16B per lane (linear dest: uniform base + lane*16).
#define GLDS16(gsrc, ldst)                                                   \
  __builtin_amdgcn_global_load_lds(                                          \
      (const __attribute__((address_space(1))) void*)(gsrc),                 \
      (__attribute__((address_space(3))) void*)(ldst), 16, 0, 0)

// ---------------------------------------------------------------------------
// fp32 -> bf16 conversion
// ---------------------------------------------------------------------------
__global__ void cvt_bf16_kernel(const float* __restrict__ src,
                                unsigned short* __restrict__ dst, int n4) {
  int i = blockIdx.x * blockDim.x + threadIdx.x;
  if (i >= n4) return;
  float4v v = reinterpret_cast<const float4v*>(src)[i];
  ushort4v o;
  o[0] = f2bf(v[0]); o[1] = f2bf(v[1]); o[2] = f2bf(v[2]); o[3] = f2bf(v[3]);
  reinterpret_cast<ushort4v*>(dst)[i] = o;
}

// ---------------------------------------------------------------------------
// m97-structure GEMM: C[M,N] = A[M,K] * B[N,K]^T, bf16 in, f32 accum.
// ---------------------------------------------------------------------------
template<bool OUT_BF16>
__global__ __launch_bounds__(256) void gemm_lds(const unsigned short* __restrict__ A,
                                                const unsigned short* __restrict__ B,
                                                void* __restrict__ Cp,
                                                int M, int N, int K) {
  __shared__ __align__(16) unsigned short As[128 * 32];
  __shared__ __align__(16) unsigned short Bs[128 * 32];

  const int tid = threadIdx.x;
  const int l = tid & 63, w = tid >> 6;
  const int wr = w >> 1, wc = w & 1;
  const int bm = blockIdx.y * 128, bn = blockIdx.x * 128;
  const int lr = l & 15, lk = (l >> 4) * 8;

  f32x4 acc[4][4] = {};

  const unsigned short* Ag0 = A + (size_t)(bm + (tid >> 2)) * K + (tid & 3) * 8;
  const unsigned short* Ag1 = A + (size_t)(bm + 64 + (tid >> 2)) * K + (tid & 3) * 8;
  const unsigned short* Bg0 = B + (size_t)(bn + (tid >> 2)) * K + (tid & 3) * 8;
  const unsigned short* Bg1 = B + (size_t)(bn + 64 + (tid >> 2)) * K + (tid & 3) * 8;
  unsigned short* Ad0 = As + tid * 8;
  unsigned short* Ad1 = As + (tid + 256) * 8;
  unsigned short* Bd0 = Bs + tid * 8;
  unsigned short* Bd1 = Bs + (tid + 256) * 8;

  const unsigned short* Afr = As + (wr * 64 + lr) * 32 + lk;
  const unsigned short* Bfr = Bs + (wc * 64 + lr) * 32 + lk;

  for (int k0 = 0; k0 < K; k0 += 32) {
    GLDS16(Ag0 + k0, Ad0);
    GLDS16(Ag1 + k0, Ad1);
    GLDS16(Bg0 + k0, Bd0);
    GLDS16(Bg1 + k0, Bd1);
    __syncthreads();

    short8 af[4], bfr[4];
#pragma unroll
    for (int mi = 0; mi < 4; mi++) af[mi]  = *(const short8*)(Afr + mi * 16 * 32);
#pragma unroll
    for (int ni = 0; ni < 4; ni++) bfr[ni] = *(const short8*)(Bfr + ni * 16 * 32);

#pragma unroll
    for (int mi = 0; mi < 4; mi++)
#pragma unroll
      for (int ni = 0; ni < 4; ni++)
        acc[mi][ni] = __builtin_amdgcn_mfma_f32_16x16x32_bf16(af[mi], bfr[ni],
                                                              acc[mi][ni], 0, 0, 0);
    __syncthreads();
  }

  const int row0 = bm + wr * 64 + (l >> 4) * 4;
  const int col0 = bn + wc * 64 + lr;
#pragma unroll
  for (int mi = 0; mi < 4; mi++)
#pragma unroll
    for (int ni = 0; ni < 4; ni++)
#pragma unroll
      for (int j = 0; j < 4; j++) {
        size_t idx = (size_t)(row0 + mi * 16 + j) * N + (col0 + ni * 16);
        if (OUT_BF16) ((unsigned short*)Cp)[idx] = f2bf(acc[mi][ni][j]);
        else          ((float*)Cp)[idx]          = acc[mi][ni][j];
      }
}

// ---------------------------------------------------------------------------
// RoPE + head reshape. Q pre-scaled by 0.125*log2e. V transposed to [H][64][S].
// ---------------------------------------------------------------------------
__global__ void rope_split_kernel(const unsigned short* __restrict__ qkv,
                                  unsigned short* __restrict__ Qr,
                                  unsigned short* __restrict__ Kr,
                                  unsigned short* __restrict__ Vt) {
  int gid = blockIdx.x * blockDim.x + threadIdx.x;  // 0 .. 4M-1
  int s = gid >> 10;
  int e = gid & 1023;
  int h = e >> 6, d = e & 63;
  size_t base = (size_t)s * 3072;

  float q = bf2f(qkv[base + e]);
  float k = bf2f(qkv[base + 1024 + e]);

  int i = d & 31;
  float inv = expf(-(float)(2 * i) * (9.2103403719761836f / 64.0f));
  float ang = (float)s * inv;
  float sn, cs;
  sincosf(ang, &sn, &cs);

  int ep = (d < 32) ? (e + 32) : (e - 32);
  float qp = bf2f(qkv[base + ep]);
  float kp = bf2f(qkv[base + 1024 + ep]);

  float qo, ko;
  if (d < 32) { qo = q * cs - qp * sn; ko = k * cs - kp * sn; }
  else        { qo = q * cs + qp * sn; ko = k * cs + kp * sn; }

  size_t oidx = ((size_t)h * S_LEN + s) * DKH + d;
  Qr[oidx] = f2bf(qo * QSCALE);
  Kr[oidx] = f2bf(ko);
  Vt[((size_t)h * DKH + d) * S_LEN + s] = qkv[base + 2048 + e];
}

// ---------------------------------------------------------------------------
// Flash attention, swapped-QK^T 32x32x16, 4-wave KV-split (shfl_xor exchanges,
// round-4 verified), bf16-packed LSE combine, setprio on MFMA clusters.
// ---------------------------------------------------------------------------
__global__ __launch_bounds__(256, 5) void flash_attn_kernel(const unsigned short* __restrict__ Qr,
                                                            const unsigned short* __restrict__ Kr,
                                                            const unsigned short* __restrict__ Vt,
                                                            unsigned short* __restrict__ O) {
  __shared__ unsigned oaccp[4][32][33];   // bf16-pair words, stride 33
  __shared__ float ml_m[4][32];
  __shared__ float ml_l[4][32];

  const int tid = threadIdx.x;
  const int l  = tid & 63;
  const int w  = tid >> 6;            // wave 0..3
  const int r  = l & 31;
  const int hi = l >> 5;

  // XCD-pinned head mapping + longest-tile-first dispatch.
  const int bx    = blockIdx.x;          // 0..2047
  const int xcd   = bx & 7;
  const int j     = bx >> 3;             // 0..255
  const int h     = xcd * 2 + (j & 1);   // 2 heads per XCD -> K/V L2-resident
  const int qtile = 127 - (j >> 1);      // longest first
  const int q0    = qtile * 32;

  const unsigned short* Qh = Qr + (size_t)h * S_LEN * DKH;
  const unsigned short* Kh = Kr + (size_t)h * S_LEN * DKH;
  const unsigned short* Vh = Vt + (size_t)h * DKH * S_LEN;

  // Q B-fragments (col=q, k=d-chunk), pre-scaled by QSCALE in rope.
  short8 qf[4];
  {
    const unsigned short* qb = Qh + (size_t)(q0 + r) * 64 + hi * 8;
#pragma unroll
    for (int dc = 0; dc < 4; dc++) qf[dc] = *(const short8*)(qb + dc * 16);
  }

  f32x16 acc0 = {}, acc1 = {};     // O^T tiles: d 0..31 / 32..63, col=q
  float m = -1e30f, lsum = 0.0f;

  // preload this wave's first K chunk
  short8 kf[4];
  {
    const unsigned short* kb = Kh + (size_t)(w * 32 + r) * 64 + hi * 8;
#pragma unroll
    for (int dc = 0; dc < 4; dc++) kf[dc] = *(const short8*)(kb + dc * 16);
  }

  for (int c = w; c <= qtile; c += 4) {
    const int kv0 = c << 5;

    // V A-frags issued early: row=d, k=key
    short8 vf[4];
    {
      const unsigned short* vb = Vh + (size_t)r * S_LEN + kv0 + hi * 8;
#pragma unroll
      for (int dt = 0; dt < 2; dt++)
#pragma unroll
        for (int kc = 0; kc < 2; kc++)
          vf[dt * 2 + kc] = *(const short8*)(vb + (size_t)dt * 32 * S_LEN + kc * 16);
    }

    // S^T = K . Q^T
    f32x16 st = {};
    __builtin_amdgcn_s_setprio(1);
    st = __builtin_amdgcn_mfma_f32_32x32x16_bf16(kf[0], qf[0], st, 0, 0, 0);
    st = __builtin_amdgcn_mfma_f32_32x32x16_bf16(kf[1], qf[1], st, 0, 0, 0);
    st = __builtin_amdgcn_mfma_f32_32x32x16_bf16(kf[2], qf[2], st, 0, 0, 0);
    st = __builtin_amdgcn_mfma_f32_32x32x16_bf16(kf[3], qf[3], st, 0, 0, 0);
    __builtin_amdgcn_s_setprio(0);

    // prefetch this wave's next K chunk under the softmax
    short8 kfn[4];
    if (c + 4 <= qtile) {
      const unsigned short* kb = Kh + (size_t)((c + 4) * 32 + r) * 64 + hi * 8;
#pragma unroll
      for (int dc = 0; dc < 4; dc++) kfn[dc] = *(const short8*)(kb + dc * 16);
    }

    // causal mask: only the diagonal chunk
    if (c == qtile) {
#pragma unroll
      for (int reg = 0; reg < 16; reg++) {
        const int koff = (reg & 3) + 8 * (reg >> 2) + 4 * hi;
        if (koff > r) st[reg] = -1e30f;
      }
    }

    // --- lane-local online softmax (exp2 domain), max3-friendly tree ---
    float t0 = fmaxf(fmaxf(st[0],  st[1]),  st[2]);
    float t1 = fmaxf(fmaxf(st[3],  st[4]),  st[5]);
    float t2 = fmaxf(fmaxf(st[6],  st[7]),  st[8]);
    float t3 = fmaxf(fmaxf(st[9],  st[10]), st[11]);
    float t4 = fmaxf(fmaxf(st[12], st[13]), st[14]);
    float pm = fmaxf(fmaxf(fmaxf(t0, t1), fmaxf(t2, t3)), fmaxf(t4, st[15]));
    pm = fmaxf(pm, __shfl_xor(pm, 32));

    // defer-max (T13, THR=8)
    if (!__all(pm <= m + 8.0f)) {
      float mn  = fmaxf(m, pm);
      float scl = exp2f(m - mn);
      m = mn;
      lsum *= scl;
#pragma unroll
      for (int reg = 0; reg < 16; reg++) { acc0[reg] *= scl; acc1[reg] *= scl; }
    }

    float p[16];
#pragma unroll
    for (int reg = 0; reg < 16; reg++) p[reg] = exp2f(st[reg] - m);

    float s2[8];
#pragma unroll
    for (int i = 0; i < 8; i++) s2[i] = p[2 * i] + p[2 * i + 1];
#pragma unroll
    for (int i = 0; i < 4; i++) s2[i] = s2[i] + s2[i + 4];
    float rs = (s2[0] + s2[2]) + (s2[1] + s2[3]);
    rs += __shfl_xor(rs, 32);
    lsum += rs;

    // --- pack P to bf16 words (round-4 verified shfl_xor exchange) ---
    unsigned wd[8];
#pragma unroll
    for (int i = 0; i < 8; i++) {
      asm("v_cvt_pk_bf16_f32 %0, %1, %2" : "=v"(wd[i]) : "v"(p[2 * i]), "v"(p[2 * i + 1]));
    }
    unsigned pw[8];
#pragma unroll
    for (int i = 0; i < 8; i++) pw[i] = __shfl_xor(wd[i], 32);

    uint4v u0, u1;
    u0[0] = hi ? pw[2] : wd[0];
    u0[1] = hi ? pw[3] : wd[1];
    u0[2] = hi ? wd[2] : pw[0];
    u0[3] = hi ? wd[3] : pw[1];
    u1[0] = hi ? pw[6] : wd[4];
    u1[1] = hi ? pw[7] : wd[5];
    u1[2] = hi ? wd[6] : pw[4];
    u1[3] = hi ? wd[7] : pw[5];
    short8 pa0 = __builtin_bit_cast(short8, u0);   // keys kv0+0..15
    short8 pa1 = __builtin_bit_cast(short8, u1);   // keys kv0+16..31

    // O^T += V^T . P
    __builtin_amdgcn_s_setprio(1);
    acc0 = __builtin_amdgcn_mfma_f32_32x32x16_bf16(vf[0], pa0, acc0, 0, 0, 0);
    acc0 = __builtin_amdgcn_mfma_f32_32x32x16_bf16(vf[1], pa1, acc0, 0, 0, 0);
    acc1 = __builtin_amdgcn_mfma_f32_32x32x16_bf16(vf[2], pa0, acc1, 0, 0, 0);
    acc1 = __builtin_amdgcn_mfma_f32_32x32x16_bf16(vf[3], pa1, acc1, 0, 0, 0);
    __builtin_amdgcn_s_setprio(0);

    if (c + 4 <= qtile) {
#pragma unroll
      for (int dc = 0; dc < 4; dc++) kf[dc] = kfn[dc];
    }
  }

  // --- LSE combine of the 4 per-wave partials (bf16-packed) ---
  if (hi == 0) { ml_m[w][r] = m; ml_l[w][r] = lsum; }
  // acc pair (2i,2i+1) -> d = 8*(i>>1)+4*hi+2*(i&1) -> word 4*(i>>1)+2*hi+(i&1)
#pragma unroll
  for (int i = 0; i < 8; i++) {
    const int widx = 4 * (i >> 1) + 2 * hi + (i & 1);
    unsigned ua, ub;
    asm("v_cvt_pk_bf16_f32 %0, %1, %2" : "=v"(ua) : "v"(acc0[2 * i]), "v"(acc0[2 * i + 1]));
    asm("v_cvt_pk_bf16_f32 %0, %1, %2" : "=v"(ub) : "v"(acc1[2 * i]), "v"(acc1[2 * i + 1]));
    oaccp[w][r][widx]      = ua;
    oaccp[w][r][16 + widx] = ub;
  }
  __syncthreads();

  const int q  = tid >> 3;          // 0..31
  const int c0 = (tid & 7) * 4;     // word index 0..28
  const float m0 = ml_m[0][q], m1 = ml_m[1][q], m2 = ml_m[2][q], m3 = ml_m[3][q];
  const float mmax = fmaxf(fmaxf(m0, m1), fmaxf(m2, m3));
  const float sc[4] = {exp2f(m0 - mmax), exp2f(m1 - mmax),
                       exp2f(m2 - mmax), exp2f(m3 - mmax)};
  const float ltot = sc[0] * ml_l[0][q] + sc[1] * ml_l[1][q] +
                     sc[2] * ml_l[2][q] + sc[3] * ml_l[3][q];
  const float rinv = 1.0f / ltot;

  float vs[8] = {};
#pragma unroll
  for (int wv = 0; wv < 4; wv++) {
#pragma unroll
    for (int i = 0; i < 4; i++) {
      unsigned u = oaccp[wv][q][c0 + i];
      vs[2 * i]     += sc[wv] * __builtin_bit_cast(float, u << 16);
      vs[2 * i + 1] += sc[wv] * __builtin_bit_cast(float, u & 0xFFFF0000u);
    }
  }
  short8 ov;
#pragma unroll
  for (int i = 0; i < 8; i++) ov[i] = (short)f2bf(vs[i] * rinv);
  *(short8*)(O + (size_t)(q0 + q) * DMODEL + h * 64 + c0 * 2) = ov;
}

// ---------------------------------------------------------------------------
// launch
// ---------------------------------------------------------------------------
extern "C" void kernel_launch(void* const* d_in, const int* in_sizes, int n_in,
                              void* d_out, int out_size, void* d_ws, size_t ws_size,
                              hipStream_t stream) {
  (void)in_sizes; (void)n_in; (void)out_size; (void)ws_size;
  const float* x    = (const float*)d_in[0];   // [4096,1024]
  const float* Wqkv = (const float*)d_in[1];   // [3072,1024]
  const float* Wo   = (const float*)d_in[2];   // [1024,1024]
  float* out = (float*)d_out;                  // [4096,1024]

  char* ws = (char*)d_ws;
  const size_t MB = 1u << 20;
  unsigned short* x_bf    = (unsigned short*)(ws + 0 * MB);
  unsigned short* wqkv_bf = (unsigned short*)(ws + 8 * MB);
  unsigned short* wo_bf   = (unsigned short*)(ws + 14 * MB);
  unsigned short* qkv_bf  = (unsigned short*)(ws + 16 * MB);
  unsigned short* Qr      = (unsigned short*)(ws + 40 * MB);
  unsigned short* Kr      = (unsigned short*)(ws + 48 * MB);
  unsigned short* Vt      = (unsigned short*)(ws + 56 * MB);
  unsigned short* Obf     = (unsigned short*)(ws + 64 * MB);

  const int n_x = 4096 * 1024, n_wqkv = 3072 * 1024, n_wo = 1024 * 1024;
  cvt_bf16_kernel<<<(n_x / 4 + 255) / 256, 256, 0, stream>>>(x, x_bf, n_x / 4);
  cvt_bf16_kernel<<<(n_wqkv / 4 + 255) / 256, 256, 0, stream>>>(Wqkv, wqkv_bf, n_wqkv / 4);
  cvt_bf16_kernel<<<(n_wo / 4 + 255) / 256, 256, 0, stream>>>(Wo, wo_bf, n_wo / 4);

  // qkv = x . Wqkv^T : M=4096, N=3072, K=1024
  gemm_lds<true><<<dim3(3072 / 128, 4096 / 128), 256, 0, stream>>>(x_bf, wqkv_bf, qkv_bf,
                                                                   4096, 3072, 1024);
  rope_split_kernel<<<(4096 * 1024) / 256, 256, 0, stream>>>(qkv_bf, Qr, Kr, Vt);

  flash_attn_kernel<<<2048, 256, 0, stream>>>(Qr, Kr, Vt, Obf);

  // out = O . Wo^T : M=4096, N=1024, K=1024
  gemm_lds<false><<<dim3(1024 / 128, 4096 / 128), 256, 0, stream>>>(Obf, wo_bf, out,
                                                                    4096, 1024, 1024);
}

// Round 8
// 229.806 us; speedup vs baseline: 1.4274x; 1.4274x over previous
//
#include <hip/hip_runtime.h>

// ---------------------------------------------------------------------------
// CausalSelfAttention fused block, MI355X (gfx950)
// Round 7: revert launch_bounds clamp (round-6 spill). Flash attention gets
// depth-2 software pipelining: QK^T(c+4) issued before softmax(c) so the
// matrix pipe overlaps the VALU softmax chain. bf16-packed LSE combine kept.
// GEMMs (m97 LDS), rope, cvt unchanged.
// ---------------------------------------------------------------------------

typedef __attribute__((ext_vector_type(8)))  short  short8;
typedef __attribute__((ext_vector_type(4)))  float  f32x4;
typedef __attribute__((ext_vector_type(16))) float  f32x16;
typedef __attribute__((ext_vector_type(4)))  float  float4v;
typedef __attribute__((ext_vector_type(4)))  unsigned short ushort4v;
typedef __attribute__((ext_vector_type(4)))  unsigned int   uint4v;

#define S_LEN 4096
#define DMODEL 1024
#define NHEADS 16
#define DKH 64

// 0.125 * log2(e): folds 1/sqrt(64) and the exp->exp2 conversion into Q.
#define QSCALE 0.18033688011112042f

__device__ __forceinline__ unsigned short f2bf(float f) {
  unsigned u = __builtin_bit_cast(unsigned, f);
  u += 0x7FFFu + ((u >> 16) & 1u);   // round-to-nearest-even
  return (unsigned short)(u >> 16);
}
__device__ __forceinline__ float bf2f(unsigned short h) {
  return __builtin_bit_cast(float, ((unsigned)h) << 16);
}

// async global->LDS, 16B per lane (linear dest: uniform base + lane*16).
#define GLDS16(gsrc, ldst)                                                   \
  __builtin_amdgcn_global_load_lds(                                          \
      (const __attribute__((address_space(1))) void*)(gsrc),                 \
      (__attribute__((address_space(3))) void*)(ldst), 16, 0, 0)

// ---------------------------------------------------------------------------
// fp32 -> bf16 conversion
// ---------------------------------------------------------------------------
__global__ void cvt_bf16_kernel(const float* __restrict__ src,
                                unsigned short* __restrict__ dst, int n4) {
  int i = blockIdx.x * blockDim.x + threadIdx.x;
  if (i >= n4) return;
  float4v v = reinterpret_cast<const float4v*>(src)[i];
  ushort4v o;
  o[0] = f2bf(v[0]); o[1] = f2bf(v[1]); o[2] = f2bf(v[2]); o[3] = f2bf(v[3]);
  reinterpret_cast<ushort4v*>(dst)[i] = o;
}

// ---------------------------------------------------------------------------
// m97-structure GEMM: C[M,N] = A[M,K] * B[N,K]^T, bf16 in, f32 accum.
// ---------------------------------------------------------------------------
template<bool OUT_BF16>
__global__ __launch_bounds__(256) void gemm_lds(const unsigned short* __restrict__ A,
                                                const unsigned short* __restrict__ B,
                                                void* __restrict__ Cp,
                                                int M, int N, int K) {
  __shared__ __align__(16) unsigned short As[128 * 32];
  __shared__ __align__(16) unsigned short Bs[128 * 32];

  const int tid = threadIdx.x;
  const int l = tid & 63, w = tid >> 6;
  const int wr = w >> 1, wc = w & 1;
  const int bm = blockIdx.y * 128, bn = blockIdx.x * 128;
  const int lr = l & 15, lk = (l >> 4) * 8;

  f32x4 acc[4][4] = {};

  const unsigned short* Ag0 = A + (size_t)(bm + (tid >> 2)) * K + (tid & 3) * 8;
  const unsigned short* Ag1 = A + (size_t)(bm + 64 + (tid >> 2)) * K + (tid & 3) * 8;
  const unsigned short* Bg0 = B + (size_t)(bn + (tid >> 2)) * K + (tid & 3) * 8;
  const unsigned short* Bg1 = B + (size_t)(bn + 64 + (tid >> 2)) * K + (tid & 3) * 8;
  unsigned short* Ad0 = As + tid * 8;
  unsigned short* Ad1 = As + (tid + 256) * 8;
  unsigned short* Bd0 = Bs + tid * 8;
  unsigned short* Bd1 = Bs + (tid + 256) * 8;

  const unsigned short* Afr = As + (wr * 64 + lr) * 32 + lk;
  const unsigned short* Bfr = Bs + (wc * 64 + lr) * 32 + lk;

  for (int k0 = 0; k0 < K; k0 += 32) {
    GLDS16(Ag0 + k0, Ad0);
    GLDS16(Ag1 + k0, Ad1);
    GLDS16(Bg0 + k0, Bd0);
    GLDS16(Bg1 + k0, Bd1);
    __syncthreads();

    short8 af[4], bfr[4];
#pragma unroll
    for (int mi = 0; mi < 4; mi++) af[mi]  = *(const short8*)(Afr + mi * 16 * 32);
#pragma unroll
    for (int ni = 0; ni < 4; ni++) bfr[ni] = *(const short8*)(Bfr + ni * 16 * 32);

#pragma unroll
    for (int mi = 0; mi < 4; mi++)
#pragma unroll
      for (int ni = 0; ni < 4; ni++)
        acc[mi][ni] = __builtin_amdgcn_mfma_f32_16x16x32_bf16(af[mi], bfr[ni],
                                                              acc[mi][ni], 0, 0, 0);
    __syncthreads();
  }

  const int row0 = bm + wr * 64 + (l >> 4) * 4;
  const int col0 = bn + wc * 64 + lr;
#pragma unroll
  for (int mi = 0; mi < 4; mi++)
#pragma unroll
    for (int ni = 0; ni < 4; ni++)
#pragma unroll
      for (int j = 0; j < 4; j++) {
        size_t idx = (size_t)(row0 + mi * 16 + j) * N + (col0 + ni * 16);
        if (OUT_BF16) ((unsigned short*)Cp)[idx] = f2bf(acc[mi][ni][j]);
        else          ((float*)Cp)[idx]          = acc[mi][ni][j];
      }
}

// ---------------------------------------------------------------------------
// RoPE + head reshape. Q pre-scaled by 0.125*log2e. V transposed to [H][64][S].
// ---------------------------------------------------------------------------
__global__ void rope_split_kernel(const unsigned short* __restrict__ qkv,
                                  unsigned short* __restrict__ Qr,
                                  unsigned short* __restrict__ Kr,
                                  unsigned short* __restrict__ Vt) {
  int gid = blockIdx.x * blockDim.x + threadIdx.x;  // 0 .. 4M-1
  int s = gid >> 10;
  int e = gid & 1023;
  int h = e >> 6, d = e & 63;
  size_t base = (size_t)s * 3072;

  float q = bf2f(qkv[base + e]);
  float k = bf2f(qkv[base + 1024 + e]);

  int i = d & 31;
  float inv = expf(-(float)(2 * i) * (9.2103403719761836f / 64.0f));
  float ang = (float)s * inv;
  float sn, cs;
  sincosf(ang, &sn, &cs);

  int ep = (d < 32) ? (e + 32) : (e - 32);
  float qp = bf2f(qkv[base + ep]);
  float kp = bf2f(qkv[base + 1024 + ep]);

  float qo, ko;
  if (d < 32) { qo = q * cs - qp * sn; ko = k * cs - kp * sn; }
  else        { qo = q * cs + qp * sn; ko = k * cs + kp * sn; }

  size_t oidx = ((size_t)h * S_LEN + s) * DKH + d;
  Qr[oidx] = f2bf(qo * QSCALE);
  Kr[oidx] = f2bf(ko);
  Vt[((size_t)h * DKH + d) * S_LEN + s] = qkv[base + 2048 + e];
}

// ---------------------------------------------------------------------------
// Flash attention, swapped-QK^T 32x32x16, 4-wave KV-split, depth-2 pipeline:
// iteration c holds st = S(c) (computed last iteration) and issues the
// QK^T for S(c+4) BEFORE the softmax of S(c), overlapping matrix and VALU
// pipes within the wave. bf16-packed LSE combine.
// ---------------------------------------------------------------------------
__global__ __launch_bounds__(256) void flash_attn_kernel(const unsigned short* __restrict__ Qr,
                                                         const unsigned short* __restrict__ Kr,
                                                         const unsigned short* __restrict__ Vt,
                                                         unsigned short* __restrict__ O) {
  __shared__ unsigned oaccp[4][32][33];   // bf16-pair words, stride 33
  __shared__ float ml_m[4][32];
  __shared__ float ml_l[4][32];

  const int tid = threadIdx.x;
  const int l  = tid & 63;
  const int w  = tid >> 6;            // wave 0..3
  const int r  = l & 31;
  const int hi = l >> 5;

  // XCD-pinned head mapping + longest-tile-first dispatch.
  const int bx    = blockIdx.x;          // 0..2047
  const int xcd   = bx & 7;
  const int j     = bx >> 3;             // 0..255
  const int h     = xcd * 2 + (j & 1);   // 2 heads per XCD -> K/V L2-resident
  const int qtile = 127 - (j >> 1);      // longest first
  const int q0    = qtile * 32;

  const unsigned short* Qh = Qr + (size_t)h * S_LEN * DKH;
  const unsigned short* Kh = Kr + (size_t)h * S_LEN * DKH;
  const unsigned short* Vh = Vt + (size_t)h * DKH * S_LEN;

  // Q B-fragments (col=q, k=d-chunk), pre-scaled by QSCALE in rope.
  short8 qf[4];
  {
    const unsigned short* qb = Qh + (size_t)(q0 + r) * 64 + hi * 8;
#pragma unroll
    for (int dc = 0; dc < 4; dc++) qf[dc] = *(const short8*)(qb + dc * 16);
  }

  f32x16 acc0 = {}, acc1 = {};     // O^T tiles: d 0..31 / 32..63, col=q
  float m = -1e30f, lsum = 0.0f;

  // --- pipeline prologue: st = S(w); kf = K(w+4) ---
  short8 kf[4];
  {
    const unsigned short* kb = Kh + (size_t)(w * 32 + r) * 64 + hi * 8;
#pragma unroll
    for (int dc = 0; dc < 4; dc++) kf[dc] = *(const short8*)(kb + dc * 16);
  }
  f32x16 st = {};
  __builtin_amdgcn_s_setprio(1);
  st = __builtin_amdgcn_mfma_f32_32x32x16_bf16(kf[0], qf[0], st, 0, 0, 0);
  st = __builtin_amdgcn_mfma_f32_32x32x16_bf16(kf[1], qf[1], st, 0, 0, 0);
  st = __builtin_amdgcn_mfma_f32_32x32x16_bf16(kf[2], qf[2], st, 0, 0, 0);
  st = __builtin_amdgcn_mfma_f32_32x32x16_bf16(kf[3], qf[3], st, 0, 0, 0);
  __builtin_amdgcn_s_setprio(0);
  if (w + 4 <= qtile) {
    const unsigned short* kb = Kh + (size_t)((w + 4) * 32 + r) * 64 + hi * 8;
#pragma unroll
    for (int dc = 0; dc < 4; dc++) kf[dc] = *(const short8*)(kb + dc * 16);
  }

  for (int c = w; c <= qtile; c += 4) {
    const int kv0 = c << 5;
    const bool has_next = (c + 4 <= qtile);

    // 1. issue QK^T for S(c+4) first — overlaps with softmax(c) below
    f32x16 stn = {};
    if (has_next) {
      __builtin_amdgcn_s_setprio(1);
      stn = __builtin_amdgcn_mfma_f32_32x32x16_bf16(kf[0], qf[0], stn, 0, 0, 0);
      stn = __builtin_amdgcn_mfma_f32_32x32x16_bf16(kf[1], qf[1], stn, 0, 0, 0);
      stn = __builtin_amdgcn_mfma_f32_32x32x16_bf16(kf[2], qf[2], stn, 0, 0, 0);
      stn = __builtin_amdgcn_mfma_f32_32x32x16_bf16(kf[3], qf[3], stn, 0, 0, 0);
      __builtin_amdgcn_s_setprio(0);
    }

    // 2. V loads for the CURRENT chunk (consumed after softmax)
    short8 vf[4];
    {
      const unsigned short* vb = Vh + (size_t)r * S_LEN + kv0 + hi * 8;
#pragma unroll
      for (int dt = 0; dt < 2; dt++)
#pragma unroll
        for (int kc = 0; kc < 2; kc++)
          vf[dt * 2 + kc] = *(const short8*)(vb + (size_t)dt * 32 * S_LEN + kc * 16);
    }

    // 3. reload kf with K(c+8), used at iteration c+4 (full-iteration cover)
    if (c + 8 <= qtile) {
      const unsigned short* kb = Kh + (size_t)((c + 8) * 32 + r) * 64 + hi * 8;
#pragma unroll
      for (int dc = 0; dc < 4; dc++) kf[dc] = *(const short8*)(kb + dc * 16);
    }

    // 4. causal mask: only the diagonal chunk
    if (c == qtile) {
#pragma unroll
      for (int reg = 0; reg < 16; reg++) {
        const int koff = (reg & 3) + 8 * (reg >> 2) + 4 * hi;
        if (koff > r) st[reg] = -1e30f;
      }
    }

    // 5. lane-local online softmax on st (exp2 domain)
    float t0 = fmaxf(fmaxf(st[0],  st[1]),  st[2]);
    float t1 = fmaxf(fmaxf(st[3],  st[4]),  st[5]);
    float t2 = fmaxf(fmaxf(st[6],  st[7]),  st[8]);
    float t3 = fmaxf(fmaxf(st[9],  st[10]), st[11]);
    float t4 = fmaxf(fmaxf(st[12], st[13]), st[14]);
    float pm = fmaxf(fmaxf(fmaxf(t0, t1), fmaxf(t2, t3)), fmaxf(t4, st[15]));
    pm = fmaxf(pm, __shfl_xor(pm, 32));

    if (!__all(pm <= m + 8.0f)) {     // defer-max (T13, THR=8)
      float mn  = fmaxf(m, pm);
      float scl = exp2f(m - mn);
      m = mn;
      lsum *= scl;
#pragma unroll
      for (int reg = 0; reg < 16; reg++) { acc0[reg] *= scl; acc1[reg] *= scl; }
    }

    float p[16];
#pragma unroll
    for (int reg = 0; reg < 16; reg++) p[reg] = exp2f(st[reg] - m);

    float s2[8];
#pragma unroll
    for (int i = 0; i < 8; i++) s2[i] = p[2 * i] + p[2 * i + 1];
#pragma unroll
    for (int i = 0; i < 4; i++) s2[i] = s2[i] + s2[i + 4];
    float rs = (s2[0] + s2[2]) + (s2[1] + s2[3]);
    rs += __shfl_xor(rs, 32);
    lsum += rs;

    // 6. pack P to bf16 B-fragments (round-4 verified shfl_xor exchange)
    unsigned wd[8];
#pragma unroll
    for (int i = 0; i < 8; i++) {
      asm("v_cvt_pk_bf16_f32 %0, %1, %2" : "=v"(wd[i]) : "v"(p[2 * i]), "v"(p[2 * i + 1]));
    }
    unsigned pw[8];
#pragma unroll
    for (int i = 0; i < 8; i++) pw[i] = __shfl_xor(wd[i], 32);

    uint4v u0, u1;
    u0[0] = hi ? pw[2] : wd[0];
    u0[1] = hi ? pw[3] : wd[1];
    u0[2] = hi ? wd[2] : pw[0];
    u0[3] = hi ? wd[3] : pw[1];
    u1[0] = hi ? pw[6] : wd[4];
    u1[1] = hi ? pw[7] : wd[5];
    u1[2] = hi ? wd[6] : pw[4];
    u1[3] = hi ? wd[7] : pw[5];
    short8 pa0 = __builtin_bit_cast(short8, u0);   // keys kv0+0..15
    short8 pa1 = __builtin_bit_cast(short8, u1);   // keys kv0+16..31

    // 7. O^T += V^T . P
    __builtin_amdgcn_s_setprio(1);
    acc0 = __builtin_amdgcn_mfma_f32_32x32x16_bf16(vf[0], pa0, acc0, 0, 0, 0);
    acc0 = __builtin_amdgcn_mfma_f32_32x32x16_bf16(vf[1], pa1, acc0, 0, 0, 0);
    acc1 = __builtin_amdgcn_mfma_f32_32x32x16_bf16(vf[2], pa0, acc1, 0, 0, 0);
    acc1 = __builtin_amdgcn_mfma_f32_32x32x16_bf16(vf[3], pa1, acc1, 0, 0, 0);
    __builtin_amdgcn_s_setprio(0);

    // 8. rotate pipeline
    st = stn;
  }

  // --- LSE combine of the 4 per-wave partials (bf16-packed) ---
  if (hi == 0) { ml_m[w][r] = m; ml_l[w][r] = lsum; }
#pragma unroll
  for (int i = 0; i < 8; i++) {
    const int widx = 4 * (i >> 1) + 2 * hi + (i & 1);
    unsigned ua, ub;
    asm("v_cvt_pk_bf16_f32 %0, %1, %2" : "=v"(ua) : "v"(acc0[2 * i]), "v"(acc0[2 * i + 1]));
    asm("v_cvt_pk_bf16_f32 %0, %1, %2" : "=v"(ub) : "v"(acc1[2 * i]), "v"(acc1[2 * i + 1]));
    oaccp[w][r][widx]      = ua;
    oaccp[w][r][16 + widx] = ub;
  }
  __syncthreads();

  const int q  = tid >> 3;          // 0..31
  const int c0 = (tid & 7) * 4;     // word index 0..28
  const float m0 = ml_m[0][q], m1 = ml_m[1][q], m2 = ml_m[2][q], m3 = ml_m[3][q];
  const float mmax = fmaxf(fmaxf(m0, m1), fmaxf(m2, m3));
  const float sc[4] = {exp2f(m0 - mmax), exp2f(m1 - mmax),
                       exp2f(m2 - mmax), exp2f(m3 - mmax)};
  const float ltot = sc[0] * ml_l[0][q] + sc[1] * ml_l[1][q] +
                     sc[2] * ml_l[2][q] + sc[3] * ml_l[3][q];
  const float rinv = 1.0f / ltot;

  float vs[8] = {};
#pragma unroll
  for (int wv = 0; wv < 4; wv++) {
#pragma unroll
    for (int i = 0; i < 4; i++) {
      unsigned u = oaccp[wv][q][c0 + i];
      vs[2 * i]     += sc[wv] * __builtin_bit_cast(float, u << 16);
      vs[2 * i + 1] += sc[wv] * __builtin_bit_cast(float, u & 0xFFFF0000u);
    }
  }
  short8 ov;
#pragma unroll
  for (int i = 0; i < 8; i++) ov[i] = (short)f2bf(vs[i] * rinv);
  *(short8*)(O + (size_t)(q0 + q) * DMODEL + h * 64 + c0 * 2) = ov;
}

// ---------------------------------------------------------------------------
// launch
// ---------------------------------------------------------------------------
extern "C" void kernel_launch(void* const* d_in, const int* in_sizes, int n_in,
                              void* d_out, int out_size, void* d_ws, size_t ws_size,
                              hipStream_t stream) {
  (void)in_sizes; (void)n_in; (void)out_size; (void)ws_size;
  const float* x    = (const float*)d_in[0];   // [4096,1024]
  const float* Wqkv = (const float*)d_in[1];   // [3072,1024]
  const float* Wo   = (const float*)d_in[2];   // [1024,1024]
  float* out = (float*)d_out;                  // [4096,1024]

  char* ws = (char*)d_ws;
  const size_t MB = 1u << 20;
  unsigned short* x_bf    = (unsigned short*)(ws + 0 * MB);
  unsigned short* wqkv_bf = (unsigned short*)(ws + 8 * MB);
  unsigned short* wo_bf   = (unsigned short*)(ws + 14 * MB);
  unsigned short* qkv_bf  = (unsigned short*)(ws + 16 * MB);
  unsigned short* Qr      = (unsigned short*)(ws + 40 * MB);
  unsigned short* Kr      = (unsigned short*)(ws + 48 * MB);
  unsigned short* Vt      = (unsigned short*)(ws + 56 * MB);
  unsigned short* Obf     = (unsigned short*)(ws + 64 * MB);

  const int n_x = 4096 * 1024, n_wqkv = 3072 * 1024, n_wo = 1024 * 1024;
  cvt_bf16_kernel<<<(n_x / 4 + 255) / 256, 256, 0, stream>>>(x, x_bf, n_x / 4);
  cvt_bf16_kernel<<<(n_wqkv / 4 + 255) / 256, 256, 0, stream>>>(Wqkv, wqkv_bf, n_wqkv / 4);
  cvt_bf16_kernel<<<(n_wo / 4 + 255) / 256, 256, 0, stream>>>(Wo, wo_bf, n_wo / 4);

  // qkv = x . Wqkv^T : M=4096, N=3072, K=1024
  gemm_lds<true><<<dim3(3072 / 128, 4096 / 128), 256, 0, stream>>>(x_bf, wqkv_bf, qkv_bf,
                                                                   4096, 3072, 1024);
  rope_split_kernel<<<(4096 * 1024) / 256, 256, 0, stream>>>(qkv_bf, Qr, Kr, Vt);

  flash_attn_kernel<<<2048, 256, 0, stream>>>(Qr, Kr, Vt, Obf);

  // out = O . Wo^T : M=4096, N=1024, K=1024
  gemm_lds<false><<<dim3(1024 / 128, 4096 / 128), 256, 0, stream>>>(Obf, wo_bf, out,
                                                                    4096, 1024, 1024);
}

// Round 9
// 194.295 us; speedup vs baseline: 1.6882x; 1.1828x over previous
//
#include <hip/hip_runtime.h>

// ---------------------------------------------------------------------------
// CausalSelfAttention fused block, MI355X (gfx950)
// Round 8: flash attention restructured to cooperative LDS-staged K/V:
// the 4 waves share a 128-key window per iteration (wave w = sub-chunk w,
// chunk c = 4*it + w, same indexing as rounds 4-7). K/V staged with
// global_load_lds + XOR swizzle (rule 21: linear dest, inverse-swz source,
// swz read). LSE combine buffer aliased onto the staging LDS (32 KB total).
// Softmax / pack / combine bodies identical to the verified round-6/7 path.
// GEMMs (m97 LDS), rope, cvt unchanged.
// ---------------------------------------------------------------------------

typedef __attribute__((ext_vector_type(8)))  short  short8;
typedef __attribute__((ext_vector_type(4)))  float  f32x4;
typedef __attribute__((ext_vector_type(16))) float  f32x16;
typedef __attribute__((ext_vector_type(4)))  float  float4v;
typedef __attribute__((ext_vector_type(4)))  unsigned short ushort4v;
typedef __attribute__((ext_vector_type(4)))  unsigned int   uint4v;

#define S_LEN 4096
#define DMODEL 1024
#define NHEADS 16
#define DKH 64

// 0.125 * log2(e): folds 1/sqrt(64) and the exp->exp2 conversion into Q.
#define QSCALE 0.18033688011112042f

__device__ __forceinline__ unsigned short f2bf(float f) {
  unsigned u = __builtin_bit_cast(unsigned, f);
  u += 0x7FFFu + ((u >> 16) & 1u);   // round-to-nearest-even
  return (unsigned short)(u >> 16);
}
__device__ __forceinline__ float bf2f(unsigned short h) {
  return __builtin_bit_cast(float, ((unsigned)h) << 16);
}

// async global->LDS, 16B per lane (linear dest: uniform base + lane*16).
#define GLDS16(gsrc, ldst)                                                   \
  __builtin_amdgcn_global_load_lds(                                          \
      (const __attribute__((address_space(1))) void*)(gsrc),                 \
      (__attribute__((address_space(3))) void*)(ldst), 16, 0, 0)

// ---------------------------------------------------------------------------
// fp32 -> bf16 conversion
// ---------------------------------------------------------------------------
__global__ void cvt_bf16_kernel(const float* __restrict__ src,
                                unsigned short* __restrict__ dst, int n4) {
  int i = blockIdx.x * blockDim.x + threadIdx.x;
  if (i >= n4) return;
  float4v v = reinterpret_cast<const float4v*>(src)[i];
  ushort4v o;
  o[0] = f2bf(v[0]); o[1] = f2bf(v[1]); o[2] = f2bf(v[2]); o[3] = f2bf(v[3]);
  reinterpret_cast<ushort4v*>(dst)[i] = o;
}

// ---------------------------------------------------------------------------
// m97-structure GEMM: C[M,N] = A[M,K] * B[N,K]^T, bf16 in, f32 accum.
// ---------------------------------------------------------------------------
template<bool OUT_BF16>
__global__ __launch_bounds__(256) void gemm_lds(const unsigned short* __restrict__ A,
                                                const unsigned short* __restrict__ B,
                                                void* __restrict__ Cp,
                                                int M, int N, int K) {
  __shared__ __align__(16) unsigned short As[128 * 32];
  __shared__ __align__(16) unsigned short Bs[128 * 32];

  const int tid = threadIdx.x;
  const int l = tid & 63, w = tid >> 6;
  const int wr = w >> 1, wc = w & 1;
  const int bm = blockIdx.y * 128, bn = blockIdx.x * 128;
  const int lr = l & 15, lk = (l >> 4) * 8;

  f32x4 acc[4][4] = {};

  const unsigned short* Ag0 = A + (size_t)(bm + (tid >> 2)) * K + (tid & 3) * 8;
  const unsigned short* Ag1 = A + (size_t)(bm + 64 + (tid >> 2)) * K + (tid & 3) * 8;
  const unsigned short* Bg0 = B + (size_t)(bn + (tid >> 2)) * K + (tid & 3) * 8;
  const unsigned short* Bg1 = B + (size_t)(bn + 64 + (tid >> 2)) * K + (tid & 3) * 8;
  unsigned short* Ad0 = As + tid * 8;
  unsigned short* Ad1 = As + (tid + 256) * 8;
  unsigned short* Bd0 = Bs + tid * 8;
  unsigned short* Bd1 = Bs + (tid + 256) * 8;

  const unsigned short* Afr = As + (wr * 64 + lr) * 32 + lk;
  const unsigned short* Bfr = Bs + (wc * 64 + lr) * 32 + lk;

  for (int k0 = 0; k0 < K; k0 += 32) {
    GLDS16(Ag0 + k0, Ad0);
    GLDS16(Ag1 + k0, Ad1);
    GLDS16(Bg0 + k0, Bd0);
    GLDS16(Bg1 + k0, Bd1);
    __syncthreads();

    short8 af[4], bfr[4];
#pragma unroll
    for (int mi = 0; mi < 4; mi++) af[mi]  = *(const short8*)(Afr + mi * 16 * 32);
#pragma unroll
    for (int ni = 0; ni < 4; ni++) bfr[ni] = *(const short8*)(Bfr + ni * 16 * 32);

#pragma unroll
    for (int mi = 0; mi < 4; mi++)
#pragma unroll
      for (int ni = 0; ni < 4; ni++)
        acc[mi][ni] = __builtin_amdgcn_mfma_f32_16x16x32_bf16(af[mi], bfr[ni],
                                                              acc[mi][ni], 0, 0, 0);
    __syncthreads();
  }

  const int row0 = bm + wr * 64 + (l >> 4) * 4;
  const int col0 = bn + wc * 64 + lr;
#pragma unroll
  for (int mi = 0; mi < 4; mi++)
#pragma unroll
    for (int ni = 0; ni < 4; ni++)
#pragma unroll
      for (int j = 0; j < 4; j++) {
        size_t idx = (size_t)(row0 + mi * 16 + j) * N + (col0 + ni * 16);
        if (OUT_BF16) ((unsigned short*)Cp)[idx] = f2bf(acc[mi][ni][j]);
        else          ((float*)Cp)[idx]          = acc[mi][ni][j];
      }
}

// ---------------------------------------------------------------------------
// RoPE + head reshape. Q pre-scaled by 0.125*log2e. V transposed to [H][64][S].
// ---------------------------------------------------------------------------
__global__ void rope_split_kernel(const unsigned short* __restrict__ qkv,
                                  unsigned short* __restrict__ Qr,
                                  unsigned short* __restrict__ Kr,
                                  unsigned short* __restrict__ Vt) {
  int gid = blockIdx.x * blockDim.x + threadIdx.x;  // 0 .. 4M-1
  int s = gid >> 10;
  int e = gid & 1023;
  int h = e >> 6, d = e & 63;
  size_t base = (size_t)s * 3072;

  float q = bf2f(qkv[base + e]);
  float k = bf2f(qkv[base + 1024 + e]);

  int i = d & 31;
  float inv = expf(-(float)(2 * i) * (9.2103403719761836f / 64.0f));
  float ang = (float)s * inv;
  float sn, cs;
  sincosf(ang, &sn, &cs);

  int ep = (d < 32) ? (e + 32) : (e - 32);
  float qp = bf2f(qkv[base + ep]);
  float kp = bf2f(qkv[base + 1024 + ep]);

  float qo, ko;
  if (d < 32) { qo = q * cs - qp * sn; ko = k * cs - kp * sn; }
  else        { qo = q * cs + qp * sn; ko = k * cs + kp * sn; }

  size_t oidx = ((size_t)h * S_LEN + s) * DKH + d;
  Qr[oidx] = f2bf(qo * QSCALE);
  Kr[oidx] = f2bf(ko);
  Vt[((size_t)h * DKH + d) * S_LEN + s] = qkv[base + 2048 + e];
}

// ---------------------------------------------------------------------------
// Flash attention, swapped-QK^T 32x32x16, LDS-staged shared K/V windows.
//
// Per iteration `it`, the block stages keys [it*128, it*128+128):
//   K tile: 128 rows x 128 B (swizzled: LDS[kr][b] = K[kr][b ^ ((kr&7)<<4)])
//   V tile:  64 rows x 256 B (swizzled likewise)
// Wave w computes chunk c = 4*it + w (same chunk->wave map as rounds 4-7).
// LSE combine buffers alias the staging LDS after the loop.
// ---------------------------------------------------------------------------
__global__ __launch_bounds__(256) void flash_attn_kernel(const unsigned short* __restrict__ Qr,
                                                         const unsigned short* __restrict__ Kr,
                                                         const unsigned short* __restrict__ Vt,
                                                         unsigned short* __restrict__ O) {
  __shared__ __align__(16) char smem[32768];   // [0,16K): K tile  [16K,32K): V tile

  const int tid = threadIdx.x;
  const int l  = tid & 63;
  const int w  = tid >> 6;            // wave 0..3
  const int r  = l & 31;
  const int hi = l >> 5;

  // XCD-pinned head mapping + longest-tile-first dispatch.
  const int bx    = blockIdx.x;          // 0..2047
  const int xcd   = bx & 7;
  const int j     = bx >> 3;             // 0..255
  const int h     = xcd * 2 + (j & 1);   // 2 heads per XCD -> K/V L2-resident
  const int qtile = 127 - (j >> 1);      // longest first
  const int q0    = qtile * 32;

  const unsigned short* Qh = Qr + (size_t)h * S_LEN * DKH;
  const unsigned short* Kh = Kr + (size_t)h * S_LEN * DKH;
  const unsigned short* Vh = Vt + (size_t)h * DKH * S_LEN;

  // --- staging constants (per thread) ---
  // K: thread t stages LDS bytes i*4096 + t*16 -> row kr = i*32 + t/8,
  //    row-byte (t%8)*16; source col = that ^ ((kr&7)<<4); kr&7 == (t/8)&7.
  const int krow  = tid >> 3;                                   // 0..31
  const int kcE   = (((tid & 7) * 16) ^ ((krow & 7) << 4)) >> 1; // elem in row
  const size_t kbase = (size_t)krow * DKH + kcE;
  // V: row vr = i*16 + t/16, row-byte (t%16)*16; vr&7 == (t/16)&7.
  const int vrow  = tid >> 4;                                   // 0..15
  const int vcE   = (((tid & 15) * 16) ^ ((vrow & 7) << 4)) >> 1;
  const size_t vbase = (size_t)vrow * S_LEN + vcE;

  // --- fragment-read constants ---
  const int sw      = (r & 7) << 4;                 // XOR swizzle for reads
  const int kfbyte  = (w * 32 + r) * 128;           // K row base (bytes)
  const int vfbyte0 = r * 256;                      // V rows r / r+32 (bytes)
  const int vfbyte1 = (r + 32) * 256;
  const int vcol    = w * 64 + hi * 16;             // V col base within row

  // Q B-fragments (col=q, k=d-chunk), pre-scaled by QSCALE in rope.
  short8 qf[4];
  {
    const unsigned short* qb = Qh + (size_t)(q0 + r) * 64 + hi * 8;
#pragma unroll
    for (int dc = 0; dc < 4; dc++) qf[dc] = *(const short8*)(qb + dc * 16);
  }

  f32x16 acc0 = {}, acc1 = {};     // O^T tiles: d 0..31 / 32..63, col=q
  float m = -1e30f, lsum = 0.0f;

  const int nwin = (qtile >> 2) + 1;
  for (int it = 0; it < nwin; it++) {
    // --- stage K (16 KB) + V (16 KB) for keys [it*128, it*128+128) ---
    {
      const unsigned short* Kg = Kh + (size_t)it * 128 * DKH;
      const unsigned short* Vg = Vh + it * 128;
#pragma unroll
      for (int i = 0; i < 4; i++) {
        GLDS16(Kg + kbase + (size_t)i * 32 * DKH, smem + i * 4096 + tid * 16);
        GLDS16(Vg + vbase + (size_t)i * 16 * S_LEN,
               smem + 16384 + i * 4096 + tid * 16);
      }
    }
    __syncthreads();

    const int c = 4 * it + w;
    if (c <= qtile) {
      // --- fragments from LDS (swizzled reads) ---
      short8 kf[4], vf[4];
#pragma unroll
      for (int dc = 0; dc < 4; dc++)
        kf[dc] = *(const short8*)(smem + kfbyte + ((dc * 32 + hi * 16) ^ sw));
#pragma unroll
      for (int kc = 0; kc < 2; kc++) {
        vf[kc]     = *(const short8*)(smem + 16384 + vfbyte0 + ((vcol + kc * 32) ^ sw));
        vf[2 + kc] = *(const short8*)(smem + 16384 + vfbyte1 + ((vcol + kc * 32) ^ sw));
      }

      // --- S^T = K . Q^T ---
      f32x16 st = {};
      __builtin_amdgcn_s_setprio(1);
      st = __builtin_amdgcn_mfma_f32_32x32x16_bf16(kf[0], qf[0], st, 0, 0, 0);
      st = __builtin_amdgcn_mfma_f32_32x32x16_bf16(kf[1], qf[1], st, 0, 0, 0);
      st = __builtin_amdgcn_mfma_f32_32x32x16_bf16(kf[2], qf[2], st, 0, 0, 0);
      st = __builtin_amdgcn_mfma_f32_32x32x16_bf16(kf[3], qf[3], st, 0, 0, 0);
      __builtin_amdgcn_s_setprio(0);

      // causal mask: only the diagonal chunk
      if (c == qtile) {
#pragma unroll
        for (int reg = 0; reg < 16; reg++) {
          const int koff = (reg & 3) + 8 * (reg >> 2) + 4 * hi;
          if (koff > r) st[reg] = -1e30f;
        }
      }

      // --- lane-local online softmax (exp2 domain) ---
      float t0 = fmaxf(fmaxf(st[0],  st[1]),  st[2]);
      float t1 = fmaxf(fmaxf(st[3],  st[4]),  st[5]);
      float t2 = fmaxf(fmaxf(st[6],  st[7]),  st[8]);
      float t3 = fmaxf(fmaxf(st[9],  st[10]), st[11]);
      float t4 = fmaxf(fmaxf(st[12], st[13]), st[14]);
      float pm = fmaxf(fmaxf(fmaxf(t0, t1), fmaxf(t2, t3)), fmaxf(t4, st[15]));
      pm = fmaxf(pm, __shfl_xor(pm, 32));

      if (!__all(pm <= m + 8.0f)) {     // defer-max (T13, THR=8)
        float mn  = fmaxf(m, pm);
        float scl = exp2f(m - mn);
        m = mn;
        lsum *= scl;
#pragma unroll
        for (int reg = 0; reg < 16; reg++) { acc0[reg] *= scl; acc1[reg] *= scl; }
      }

      float p[16];
#pragma unroll
      for (int reg = 0; reg < 16; reg++) p[reg] = exp2f(st[reg] - m);

      float s2[8];
#pragma unroll
      for (int i = 0; i < 8; i++) s2[i] = p[2 * i] + p[2 * i + 1];
#pragma unroll
      for (int i = 0; i < 4; i++) s2[i] = s2[i] + s2[i + 4];
      float rs = (s2[0] + s2[2]) + (s2[1] + s2[3]);
      rs += __shfl_xor(rs, 32);
      lsum += rs;

      // --- pack P to bf16 B-fragments (verified shfl_xor exchange) ---
      unsigned wd[8];
#pragma unroll
      for (int i = 0; i < 8; i++) {
        asm("v_cvt_pk_bf16_f32 %0, %1, %2" : "=v"(wd[i]) : "v"(p[2 * i]), "v"(p[2 * i + 1]));
      }
      unsigned pw[8];
#pragma unroll
      for (int i = 0; i < 8; i++) pw[i] = __shfl_xor(wd[i], 32);

      uint4v u0, u1;
      u0[0] = hi ? pw[2] : wd[0];
      u0[1] = hi ? pw[3] : wd[1];
      u0[2] = hi ? wd[2] : pw[0];
      u0[3] = hi ? wd[3] : pw[1];
      u1[0] = hi ? pw[6] : wd[4];
      u1[1] = hi ? pw[7] : wd[5];
      u1[2] = hi ? wd[6] : pw[4];
      u1[3] = hi ? wd[7] : pw[5];
      short8 pa0 = __builtin_bit_cast(short8, u0);   // keys c*32+0..15
      short8 pa1 = __builtin_bit_cast(short8, u1);   // keys c*32+16..31

      // --- O^T += V^T . P ---
      __builtin_amdgcn_s_setprio(1);
      acc0 = __builtin_amdgcn_mfma_f32_32x32x16_bf16(vf[0], pa0, acc0, 0, 0, 0);
      acc0 = __builtin_amdgcn_mfma_f32_32x32x16_bf16(vf[1], pa1, acc0, 0, 0, 0);
      acc1 = __builtin_amdgcn_mfma_f32_32x32x16_bf16(vf[2], pa0, acc1, 0, 0, 0);
      acc1 = __builtin_amdgcn_mfma_f32_32x32x16_bf16(vf[3], pa1, acc1, 0, 0, 0);
      __builtin_amdgcn_s_setprio(0);
    }
    __syncthreads();   // protect LDS before next window's staging
  }

  // --- LSE combine (buffers alias the staging LDS; loop's last barrier
  //     guarantees all K/V reads are done) ---
  unsigned (*oaccp)[32][33] = (unsigned (*)[32][33])smem;         // 16896 B
  float* mlm = (float*)(smem + 16896);                            //   512 B
  float* mll = (float*)(smem + 17408);                            //   512 B

  if (hi == 0) { mlm[w * 32 + r] = m; mll[w * 32 + r] = lsum; }
#pragma unroll
  for (int i = 0; i < 8; i++) {
    const int widx = 4 * (i >> 1) + 2 * hi + (i & 1);
    unsigned ua, ub;
    asm("v_cvt_pk_bf16_f32 %0, %1, %2" : "=v"(ua) : "v"(acc0[2 * i]), "v"(acc0[2 * i + 1]));
    asm("v_cvt_pk_bf16_f32 %0, %1, %2" : "=v"(ub) : "v"(acc1[2 * i]), "v"(acc1[2 * i + 1]));
    oaccp[w][r][widx]      = ua;
    oaccp[w][r][16 + widx] = ub;
  }
  __syncthreads();

  const int q  = tid >> 3;          // 0..31
  const int c0 = (tid & 7) * 4;     // word index 0..28
  const float m0 = mlm[q], m1 = mlm[32 + q], m2 = mlm[64 + q], m3 = mlm[96 + q];
  const float mmax = fmaxf(fmaxf(m0, m1), fmaxf(m2, m3));
  const float sc[4] = {exp2f(m0 - mmax), exp2f(m1 - mmax),
                       exp2f(m2 - mmax), exp2f(m3 - mmax)};
  const float ltot = sc[0] * mll[q] + sc[1] * mll[32 + q] +
                     sc[2] * mll[64 + q] + sc[3] * mll[96 + q];
  const float rinv = 1.0f / ltot;

  float vs[8] = {};
#pragma unroll
  for (int wv = 0; wv < 4; wv++) {
#pragma unroll
    for (int i = 0; i < 4; i++) {
      unsigned u = oaccp[wv][q][c0 + i];
      vs[2 * i]     += sc[wv] * __builtin_bit_cast(float, u << 16);
      vs[2 * i + 1] += sc[wv] * __builtin_bit_cast(float, u & 0xFFFF0000u);
    }
  }
  short8 ov;
#pragma unroll
  for (int i = 0; i < 8; i++) ov[i] = (short)f2bf(vs[i] * rinv);
  *(short8*)(O + (size_t)(q0 + q) * DMODEL + h * 64 + c0 * 2) = ov;
}

// ---------------------------------------------------------------------------
// launch
// ---------------------------------------------------------------------------
extern "C" void kernel_launch(void* const* d_in, const int* in_sizes, int n_in,
                              void* d_out, int out_size, void* d_ws, size_t ws_size,
                              hipStream_t stream) {
  (void)in_sizes; (void)n_in; (void)out_size; (void)ws_size;
  const float* x    = (const float*)d_in[0];   // [4096,1024]
  const float* Wqkv = (const float*)d_in[1];   // [3072,1024]
  const float* Wo   = (const float*)d_in[2];   // [1024,1024]
  float* out = (float*)d_out;                  // [4096,1024]

  char* ws = (char*)d_ws;
  const size_t MB = 1u << 20;
  unsigned short* x_bf    = (unsigned short*)(ws + 0 * MB);
  unsigned short* wqkv_bf = (unsigned short*)(ws + 8 * MB);
  unsigned short* wo_bf   = (unsigned short*)(ws + 14 * MB);
  unsigned short* qkv_bf  = (unsigned short*)(ws + 16 * MB);
  unsigned short* Qr      = (unsigned short*)(ws + 40 * MB);
  unsigned short* Kr      = (unsigned short*)(ws + 48 * MB);
  unsigned short* Vt      = (unsigned short*)(ws + 56 * MB);
  unsigned short* Obf     = (unsigned short*)(ws + 64 * MB);

  const int n_x = 4096 * 1024, n_wqkv = 3072 * 1024, n_wo = 1024 * 1024;
  cvt_bf16_kernel<<<(n_x / 4 + 255) / 256, 256, 0, stream>>>(x, x_bf, n_x / 4);
  cvt_bf16_kernel<<<(n_wqkv / 4 + 255) / 256, 256, 0, stream>>>(Wqkv, wqkv_bf, n_wqkv / 4);
  cvt_bf16_kernel<<<(n_wo / 4 + 255) / 256, 256, 0, stream>>>(Wo, wo_bf, n_wo / 4);

  // qkv = x . Wqkv^T : M=4096, N=3072, K=1024
  gemm_lds<true><<<dim3(3072 / 128, 4096 / 128), 256, 0, stream>>>(x_bf, wqkv_bf, qkv_bf,
                                                                   4096, 3072, 1024);
  rope_split_kernel<<<(4096 * 1024) / 256, 256, 0, stream>>>(qkv_bf, Qr, Kr, Vt);

  flash_attn_kernel<<<2048, 256, 0, stream>>>(Qr, Kr, Vt, Obf);

  // out = O . Wo^T : M=4096, N=1024, K=1024
  gemm_lds<false><<<dim3(1024 / 128, 4096 / 128), 256, 0, stream>>>(Obf, wo_bf, out,
                                                                    4096, 1024, 1024);
}